// Round 10
// baseline (2763.608 us; speedup 1.0000x reference)
//
#include <hip/hip_runtime.h>
#include <stdint.h>

#define M_DIM 8192
#define N_DIM 4096
#define K_DIM 4096
#define CBN   (K_DIM/8)   // 512 column groups per row

typedef __attribute__((ext_vector_type(8))) short bf16x8;
typedef __attribute__((ext_vector_type(8))) unsigned short u16x8;
typedef __attribute__((ext_vector_type(4))) float f32x4;

#define AS_GLOBAL(p) (const __attribute__((address_space(1))) void*)(p)
#define AS_LDS(p)    (__attribute__((address_space(3))) void*)(p)

static __device__ __forceinline__ unsigned short f2bf(float f) {
    union { float f; uint32_t u; } c; c.f = f;
    uint32_t u = c.u;
    return (unsigned short)((u + 0x7fffu + ((u >> 16) & 1u)) >> 16);
}

// ---------------------------------------------------------------------------
// Kernel 1: per (ob, cb) pick top-4 columns (of 8) by L1 mass over 64 rows.
// ---------------------------------------------------------------------------
__global__ __launch_bounds__(256) void venom_sel(const float* __restrict__ W,
                                                 uint16_t* __restrict__ sel) {
    int t   = threadIdx.x;
    int ob  = blockIdx.x;
    int col = blockIdx.y * 256 + t;
    const float* p = W + (size_t)(ob * 64) * K_DIM + col;
    double s = 0.0;
    #pragma unroll 16
    for (int r = 0; r < 64; ++r) s += fabsf(p[(size_t)r * K_DIM]);

    int lane = t & 63;
    int base = lane & ~7;
    double sc[8];
    #pragma unroll
    for (int j = 0; j < 8; ++j) sc[j] = __shfl(s, base + j, 64);

    uint32_t packed = 0;
    #pragma unroll
    for (int c = 0; c < 8; ++c) {
        int rank = 0;
        #pragma unroll
        for (int j = 0; j < 8; ++j)
            rank += (sc[j] > sc[c]) || (sc[j] == sc[c] && j < c);
        if (rank < 4) packed |= (uint32_t)c << (4 * rank);
    }
    if ((lane & 7) == 0) {
        int cb = col >> 3;
        sel[ob * CBN + cb] = (uint16_t)packed;
    }
}

// ---------------------------------------------------------------------------
// Kernel 2: masked bf16 weight pack (top-2 of selected 4 by |w|).
// ---------------------------------------------------------------------------
__global__ __launch_bounds__(256) void venom_pack(const float* __restrict__ W,
                                                  const uint16_t* __restrict__ sel,
                                                  unsigned short* __restrict__ Wb) {
    int gid = blockIdx.x * 256 + threadIdx.x;
    int o  = gid >> 9;
    int cb = gid & (CBN - 1);
    uint32_t pk = sel[(o >> 6) * CBN + cb];
    const float* p = W + (size_t)o * K_DIM + cb * 8;
    float4 a = *(const float4*)p;
    float4 b = *(const float4*)(p + 4);
    float w[8] = {a.x, a.y, a.z, a.w, b.x, b.y, b.z, b.w};

    int   c[4]; float v[4];
    #pragma unroll
    for (int pz = 0; pz < 4; ++pz) {
        c[pz] = (pk >> (4 * pz)) & 7;
        v[pz] = fabsf(w[c[pz]]);
    }
    uint32_t keep = 0;
    #pragma unroll
    for (int pz = 0; pz < 4; ++pz) {
        int cnt = 0;
        #pragma unroll
        for (int q = 0; q < 4; ++q)
            cnt += (v[q] > v[pz]) || (v[q] == v[pz] && q < pz);
        if (cnt < 2) keep |= 1u << c[pz];
    }
    u16x8 out;
    #pragma unroll
    for (int j = 0; j < 8; ++j)
        out[j] = f2bf(((keep >> j) & 1) ? w[j] : 0.0f);
    *(u16x8*)(Wb + (size_t)gid * 8) = out;
}

// ---------------------------------------------------------------------------
// Kernel 3: x f32 -> bf16 (RNE).
// ---------------------------------------------------------------------------
__global__ __launch_bounds__(256) void xcvt(const float* __restrict__ X,
                                            unsigned short* __restrict__ Xb) {
    size_t gid = (size_t)blockIdx.x * 256 + threadIdx.x;
    const float4* p = (const float4*)X + gid * 2;
    float4 a = p[0], b = p[1];
    float w[8] = {a.x, a.y, a.z, a.w, b.x, b.y, b.z, b.w};
    u16x8 out;
    #pragma unroll
    for (int j = 0; j < 8; ++j) out[j] = f2bf(w[j]);
    *(u16x8*)(Xb + gid * 8) = out;
}

// ---------------------------------------------------------------------------
// Kernel 4: 256x256 bf16 GEMM, PARITY-SPLIT wave schedule. One SP per 32-K
// slice, one barrier per SP, regions cycle mod 4.
//   wm==0 waves: { read slice s (12 ds_read) | lgkm(0) | 32 MFMA }
//   wm==1 waves: { lgkm(0) [tail reads from SP s-1] | 32 MFMA | read s+1 }
// -> at any instant half the waves MFMA while the other half's reads are in
// LDS service; the all-wave post-barrier read flood (which serialized the
// 1152cy LDS window with the 1242cy MFMA window in rounds 3-9, ~50% MfmaUtil)
// is gone. Parity pairs {k,k+4} share a SIMD (wid%4 mapping) -> every SIMD
// always has one MFMA-active wave.
// Shared per SP: stage slice s+3 (4 gload_lds) | vmcnt(4) | s_barrier.
// Ledger: R-after-W: wm1 reads s+1 @SP s: staged @s-2, drained CKPT4@s-1
//   (outstanding stage(s-1)+stage(s)=8 -> drains s-2... i.e. slice s+1) +BAR.
//   wm0 reads s @SP s: same region, one SP later ✓. W-after-R: stage@SP s
//   overwrites region of slice s-1: wm0's reads of it drained @SP s-1 top
//   lgkm(0); wm1's tail reads of it (@SP s-2) drained @their SP s-1 top
//   lgkm(0); both before BAR(s-1) < stage@s ✓.
// Tail: CKPT4@124 drains stage@123 (slice 126, read @125 tail); CKPT0@125
//   drains stage@124 (slice 127, read @126 tail / @127 top); SP127 no reads.
// Frags 16x16x32 (0 conflicts); XOR chunk swizzle; XCD block swizzle.
// ---------------------------------------------------------------------------
__global__ __launch_bounds__(512, 2) void gemm256(const unsigned short* __restrict__ A,
                                                  const unsigned short* __restrict__ B,
                                                  const float* __restrict__ bias,
                                                  float* __restrict__ C) {
    __shared__ __align__(16) unsigned char smem[131072]; // A:[0,64K) B:[64K,128K)

    int t    = threadIdx.x;
    int wid  = t >> 6;
    int lane = t & 63;
    int l16  = lane & 15;
    int lk   = lane >> 4;
    int wm   = wid >> 2;     // wave row-half (128 rows) == schedule parity
    int wn   = wid & 3;      // wave col-quarter (64 cols)

    // XCD-aware bijective swizzle (512 blocks % 8 == 0)
    int bid = blockIdx.x;
    int swz = (bid & 7) * ((int)gridDim.x >> 3) + (bid >> 3);
    int bm  = swz >> 4;
    int bn  = swz & 15;

    // staging: thread t covers row r=t>>2 (and r+128), phys chunk t&3 holds
    // logical chunk (t&3)^((r>>1)&3) = (t&3)^((t>>3)&3)
    int gch = ((t & 3) ^ ((t >> 3) & 3)) * 8;
    const unsigned short* agbase = A + (size_t)(bm * 256 + (t >> 2)) * K_DIM + gch;
    const unsigned short* bgbase = B + (size_t)(bn * 256 + (t >> 2)) * K_DIM + gch;

    auto stageA2 = [&](int slice) {
        const unsigned short* ga = agbase + slice * 32;
        char* la = (char*)smem + (slice & 3) * 16384 + wid * 1024;
        __builtin_amdgcn_global_load_lds(AS_GLOBAL(ga), AS_LDS(la), 16, 0, 0);
        __builtin_amdgcn_global_load_lds(AS_GLOBAL(ga + (size_t)128 * K_DIM), AS_LDS(la + 8192), 16, 0, 0);
    };
    auto stageB2 = [&](int slice) {
        const unsigned short* gb = bgbase + slice * 32;
        char* lb = (char*)smem + 65536 + (slice & 3) * 16384 + wid * 1024;
        __builtin_amdgcn_global_load_lds(AS_GLOBAL(gb), AS_LDS(lb), 16, 0, 0);
        __builtin_amdgcn_global_load_lds(AS_GLOBAL(gb + (size_t)128 * K_DIM), AS_LDS(lb + 8192), 16, 0, 0);
    };

    // read-side: row R = base+l16, k-chunk lk -> phys chunk lk^((l16>>1)&3)
    int koff = ((lk ^ ((l16 >> 1) & 3)) << 4);
    const char* ardb = (const char*)smem + (wm * 128 + l16) * 64 + koff;
    const char* brdb = (const char*)smem + 65536 + (wn * 64 + l16) * 64 + koff;

    f32x4 acc[8][4] = {};
    bf16x8 af0[4], af1[4], bfr[4];

#define LGKM0() { asm volatile("s_waitcnt lgkmcnt(0)" ::: "memory");                 \
                  __builtin_amdgcn_sched_barrier(0); }
#define CKPT4() { asm volatile("s_waitcnt vmcnt(4)" ::: "memory");                   \
                  __builtin_amdgcn_sched_barrier(0); }
#define CKPT0() { asm volatile("s_waitcnt vmcnt(0)" ::: "memory");                   \
                  __builtin_amdgcn_sched_barrier(0); }
#define BAR()   { __builtin_amdgcn_s_barrier(); __builtin_amdgcn_sched_barrier(0); }

#define RDNXT(RN)                                                                    \
    {                                                                                \
        _Pragma("unroll")                                                            \
        for (int g = 0; g < 4; ++g)                                                  \
            bfr[g] = *(const bf16x8*)(brdb + (RN) * 16384 + g * 1024);               \
        _Pragma("unroll")                                                            \
        for (int i = 0; i < 4; ++i)                                                  \
            af0[i] = *(const bf16x8*)(ardb + (RN) * 16384 + i * 1024);               \
        _Pragma("unroll")                                                            \
        for (int i = 0; i < 4; ++i)                                                  \
            af1[i] = *(const bf16x8*)(ardb + (RN) * 16384 + 4096 + i * 1024);        \
        __builtin_amdgcn_sched_barrier(0);                                           \
    }

#define MFMA32()                                                                     \
    {                                                                                \
        __builtin_amdgcn_s_setprio(1);                                               \
        _Pragma("unroll")                                                            \
        for (int i = 0; i < 4; ++i)                                                  \
            _Pragma("unroll")                                                        \
            for (int g = 0; g < 4; ++g)                                              \
                acc[i][g] = __builtin_amdgcn_mfma_f32_16x16x32_bf16(af0[i], bfr[g], acc[i][g], 0, 0, 0); \
        _Pragma("unroll")                                                            \
        for (int i = 0; i < 4; ++i)                                                  \
            _Pragma("unroll")                                                        \
            for (int g = 0; g < 4; ++g)                                              \
                acc[4+i][g] = __builtin_amdgcn_mfma_f32_16x16x32_bf16(af1[i], bfr[g], acc[4+i][g], 0, 0, 0); \
        __builtin_amdgcn_s_setprio(0);                                               \
        __builtin_amdgcn_sched_barrier(0);                                           \
    }

    // SP: RC = region of slice s (wm0 reads at top); RNX = region of s+1
    // (wm1 reads at tail, if DORD); stage slice SS if DOSTAGE; CK: 4/1/0.
#define SPX(RC, RNX, DORD, DOSTAGE, SS, CK)                                          \
    {                                                                                \
        if (wm == 0) {                                                               \
            RDNXT(RC)                                                                \
            LGKM0()                                                                  \
            MFMA32()                                                                 \
        } else {                                                                     \
            LGKM0()                                                                  \
            MFMA32()                                                                 \
            if (DORD) RDNXT(RNX)                                                     \
        }                                                                            \
        if (DOSTAGE) { stageA2(SS); stageB2(SS); }                                   \
        if ((CK) == 4) { CKPT4() } else if ((CK) == 1) { CKPT0() }                   \
        BAR()                                                                        \
    }

    // prologue: stage slices 0,1,2; drain 0,1 (12 outstanding -> vmcnt(4));
    // barrier; wm1 waves pre-read slice 0.
    stageA2(0); stageB2(0);
    stageA2(1); stageB2(1);
    stageA2(2); stageB2(2);
    CKPT4()
    BAR()
    if (wm == 1) RDNXT(0)

    // slices 0..123 uniform (stage s+3 <= 126)
    for (int s4 = 0; s4 < 31; ++s4) {
        int s = s4 * 4;
        SPX(0, 1, 1, 1, s + 3, 4)
        SPX(1, 2, 1, 1, s + 4, 4)
        SPX(2, 3, 1, 1, s + 5, 4)
        SPX(3, 0, 1, 1, s + 6, 4)
    }
    // tail: s = 124..127
    SPX(0, 1, 1, 1, 127, 4)   // s=124: stage 127; drain stage@123 (slice 126)
    SPX(1, 2, 1, 0, 0,   1)   // s=125: CKPT0 drains stage@124 (slice 127)
    SPX(2, 3, 1, 0, 0,   0)   // s=126: wm1 tail-reads slice 127
    SPX(3, 0, 0, 0, 0,   0)   // s=127: no reads after

    // epilogue: C/D layout col = lane&15, row = (lane>>4)*4 + reg
    int    colb = bn * 256 + wn * 64;
    size_t rowb = (size_t)bm * 256 + wm * 128 + (lk << 2);
    #pragma unroll
    for (int g = 0; g < 4; ++g) {
        int col = colb + g * 16 + l16;
        float bv = bias[col];
        #pragma unroll
        for (int f = 0; f < 8; ++f) {
            size_t r0 = rowb + f * 16;
            #pragma unroll
            for (int rg = 0; rg < 4; ++rg)
                C[(r0 + rg) * N_DIM + col] = acc[f][g][rg] + bv;
        }
    }
}

extern "C" void kernel_launch(void* const* d_in, const int* in_sizes, int n_in,
                              void* d_out, int out_size, void* d_ws, size_t ws_size,
                              hipStream_t stream) {
    const float* x    = (const float*)d_in[0];
    const float* W    = (const float*)d_in[1];
    const float* bias = (const float*)d_in[2];
    float* out = (float*)d_out;

    char* ws = (char*)d_ws;
    unsigned short* xb  = (unsigned short*)ws;                                   // 64 MB
    unsigned short* wb  = (unsigned short*)(ws + (size_t)M_DIM * K_DIM * 2);     // 32 MB
    uint16_t*       sel = (uint16_t*)(ws + (size_t)M_DIM * K_DIM * 2
                                         + (size_t)N_DIM * K_DIM * 2);           // 64 KB

    venom_sel <<<dim3(64, 16), 256, 0, stream>>>(W, sel);
    venom_pack<<<dim3((N_DIM * CBN) / 256), 256, 0, stream>>>(W, sel, wb);
    xcvt      <<<dim3((M_DIM * K_DIM / 8) / 256), 256, 0, stream>>>(x, xb);
    gemm256   <<<dim3((M_DIM / 256) * (N_DIM / 256)), 512, 0, stream>>>(xb, wb, bias, out);
}

// Round 11
// 281.524 us; speedup vs baseline: 9.8166x; 9.8166x over previous
//
#include <hip/hip_runtime.h>
#include <stdint.h>

#define M_DIM 8192
#define N_DIM 4096
#define K_DIM 4096
#define CBN   (K_DIM/8)   // 512 column groups per row

typedef __attribute__((ext_vector_type(8))) short bf16x8;
typedef __attribute__((ext_vector_type(8))) unsigned short u16x8;
typedef __attribute__((ext_vector_type(4))) float f32x4;

#define AS_GLOBAL(p) (const __attribute__((address_space(1))) void*)(p)
#define AS_LDS(p)    (__attribute__((address_space(3))) void*)(p)

static __device__ __forceinline__ unsigned short f2bf(float f) {
    union { float f; uint32_t u; } c; c.f = f;
    uint32_t u = c.u;
    return (unsigned short)((u + 0x7fffu + ((u >> 16) & 1u)) >> 16);
}

// ---------------------------------------------------------------------------
// Kernel 1: per (ob, cb) pick top-4 columns (of 8) by L1 mass over 64 rows.
// ---------------------------------------------------------------------------
__global__ __launch_bounds__(256) void venom_sel(const float* __restrict__ W,
                                                 uint16_t* __restrict__ sel) {
    int t   = threadIdx.x;
    int ob  = blockIdx.x;
    int col = blockIdx.y * 256 + t;
    const float* p = W + (size_t)(ob * 64) * K_DIM + col;
    double s = 0.0;
    #pragma unroll 16
    for (int r = 0; r < 64; ++r) s += fabsf(p[(size_t)r * K_DIM]);

    int lane = t & 63;
    int base = lane & ~7;
    double sc[8];
    #pragma unroll
    for (int j = 0; j < 8; ++j) sc[j] = __shfl(s, base + j, 64);

    uint32_t packed = 0;
    #pragma unroll
    for (int c = 0; c < 8; ++c) {
        int rank = 0;
        #pragma unroll
        for (int j = 0; j < 8; ++j)
            rank += (sc[j] > sc[c]) || (sc[j] == sc[c] && j < c);
        if (rank < 4) packed |= (uint32_t)c << (4 * rank);
    }
    if ((lane & 7) == 0) {
        int cb = col >> 3;
        sel[ob * CBN + cb] = (uint16_t)packed;
    }
}

// ---------------------------------------------------------------------------
// Kernel 2: masked bf16 weight pack (top-2 of selected 4 by |w|).
// ---------------------------------------------------------------------------
__global__ __launch_bounds__(256) void venom_pack(const float* __restrict__ W,
                                                  const uint16_t* __restrict__ sel,
                                                  unsigned short* __restrict__ Wb) {
    int gid = blockIdx.x * 256 + threadIdx.x;
    int o  = gid >> 9;
    int cb = gid & (CBN - 1);
    uint32_t pk = sel[(o >> 6) * CBN + cb];
    const float* p = W + (size_t)o * K_DIM + cb * 8;
    float4 a = *(const float4*)p;
    float4 b = *(const float4*)(p + 4);
    float w[8] = {a.x, a.y, a.z, a.w, b.x, b.y, b.z, b.w};

    int   c[4]; float v[4];
    #pragma unroll
    for (int pz = 0; pz < 4; ++pz) {
        c[pz] = (pk >> (4 * pz)) & 7;
        v[pz] = fabsf(w[c[pz]]);
    }
    uint32_t keep = 0;
    #pragma unroll
    for (int pz = 0; pz < 4; ++pz) {
        int cnt = 0;
        #pragma unroll
        for (int q = 0; q < 4; ++q)
            cnt += (v[q] > v[pz]) || (v[q] == v[pz] && q < pz);
        if (cnt < 2) keep |= 1u << c[pz];
    }
    u16x8 out;
    #pragma unroll
    for (int j = 0; j < 8; ++j)
        out[j] = f2bf(((keep >> j) & 1) ? w[j] : 0.0f);
    *(u16x8*)(Wb + (size_t)gid * 8) = out;
}

// ---------------------------------------------------------------------------
// Kernel 3: x f32 -> bf16 (RNE).
// ---------------------------------------------------------------------------
__global__ __launch_bounds__(256) void xcvt(const float* __restrict__ X,
                                            unsigned short* __restrict__ Xb) {
    size_t gid = (size_t)blockIdx.x * 256 + threadIdx.x;
    const float4* p = (const float4*)X + gid * 2;
    float4 a = p[0], b = p[1];
    float w[8] = {a.x, a.y, a.z, a.w, b.x, b.y, b.z, b.w};
    u16x8 out;
    #pragma unroll
    for (int j = 0; j < 8; ++j) out[j] = f2bf(w[j]);
    *(u16x8*)(Xb + gid * 8) = out;
}

// ---------------------------------------------------------------------------
// Kernel 4: 256x256 bf16 GEMM, PARITY-SPLIT schedule with SEPARATED loops
// (round-10 semantics, straight-line codegen — no per-SP divergence, no
// frag-register spill). One SP per 32-K slice, 1 barrier/SP, regions mod 4,
// stage lead 3 (slice s+3 staged at SP s).
//   wm==0 loop: SP s = { read s | stage s+3 | lgkm(0) | 32 MFMA | vmcnt | BAR }
//   wm==1 loop: SP s = { lgkm(0) | 32 MFMA (frags from tail of s-1)
//                        | read s+1 | stage s+3 | vmcnt | BAR }
// Post-barrier: wm1 waves (one per SIMD) enter MFMA immediately while wm0
// waves' 48-read flood is in LDS service -> the 1152cy LDS window overlaps
// the 1242cy MFMA window instead of serializing (rounds 3-9: ~50% MfmaUtil).
// Ledger (identical to round 10, which PASSED):
//   R-after-W: wm0 reads s @SP s: staged @s-3, drained CKPT4@s-2 + BAR.
//     wm1 reads s+1 @tail of SP s: staged @s-2, drained CKPT4@s-1 + BAR@s-1.
//   W-after-R: stage@s overwrites region of s-1; wm0 read it @top s-1
//     (lgkm0-drained pre-BAR@s-1), wm1 @tail s-2 (drained by their lgkm0
//     @top s-1) -> both before BAR@s-1 < stage@s.
//   Tail: CKPT4@124 (drains stage@123=slice126), CKPT0@125 (drains
//     stage@124=slice127), none @126/127. Barrier counts equal in both loops.
// Frags 16x16x32 (0 conflicts); XOR chunk swizzle; XCD block swizzle.
// ---------------------------------------------------------------------------
__global__ __launch_bounds__(512, 2) void gemm256(const unsigned short* __restrict__ A,
                                                  const unsigned short* __restrict__ B,
                                                  const float* __restrict__ bias,
                                                  float* __restrict__ C) {
    __shared__ __align__(16) unsigned char smem[131072]; // A:[0,64K) B:[64K,128K)

    int t    = threadIdx.x;
    int wid  = t >> 6;
    int lane = t & 63;
    int l16  = lane & 15;
    int lk   = lane >> 4;
    int wm   = wid >> 2;     // wave row-half (128 rows) == schedule parity
    int wn   = wid & 3;      // wave col-quarter (64 cols)

    // XCD-aware bijective swizzle (512 blocks % 8 == 0)
    int bid = blockIdx.x;
    int swz = (bid & 7) * ((int)gridDim.x >> 3) + (bid >> 3);
    int bm  = swz >> 4;
    int bn  = swz & 15;

    // staging: thread t covers row r=t>>2 (and r+128), phys chunk t&3 holds
    // logical chunk (t&3)^((r>>1)&3) = (t&3)^((t>>3)&3)
    int gch = ((t & 3) ^ ((t >> 3) & 3)) * 8;
    const unsigned short* agbase = A + (size_t)(bm * 256 + (t >> 2)) * K_DIM + gch;
    const unsigned short* bgbase = B + (size_t)(bn * 256 + (t >> 2)) * K_DIM + gch;

    auto stageA2 = [&](int slice) {
        const unsigned short* ga = agbase + slice * 32;
        char* la = (char*)smem + (slice & 3) * 16384 + wid * 1024;
        __builtin_amdgcn_global_load_lds(AS_GLOBAL(ga), AS_LDS(la), 16, 0, 0);
        __builtin_amdgcn_global_load_lds(AS_GLOBAL(ga + (size_t)128 * K_DIM), AS_LDS(la + 8192), 16, 0, 0);
    };
    auto stageB2 = [&](int slice) {
        const unsigned short* gb = bgbase + slice * 32;
        char* lb = (char*)smem + 65536 + (slice & 3) * 16384 + wid * 1024;
        __builtin_amdgcn_global_load_lds(AS_GLOBAL(gb), AS_LDS(lb), 16, 0, 0);
        __builtin_amdgcn_global_load_lds(AS_GLOBAL(gb + (size_t)128 * K_DIM), AS_LDS(lb + 8192), 16, 0, 0);
    };

    // read-side: row R = base+l16, k-chunk lk -> phys chunk lk^((l16>>1)&3)
    int koff = ((lk ^ ((l16 >> 1) & 3)) << 4);
    const char* ardb = (const char*)smem + (wm * 128 + l16) * 64 + koff;
    const char* brdb = (const char*)smem + 65536 + (wn * 64 + l16) * 64 + koff;

    f32x4 acc[8][4] = {};
    bf16x8 af0[4], af1[4], bfr[4];

#define LGKM0() { asm volatile("s_waitcnt lgkmcnt(0)" ::: "memory");                 \
                  __builtin_amdgcn_sched_barrier(0); }
#define CKPT4() { asm volatile("s_waitcnt vmcnt(4)" ::: "memory");                   \
                  __builtin_amdgcn_sched_barrier(0); }
#define CKPT0() { asm volatile("s_waitcnt vmcnt(0)" ::: "memory");                   \
                  __builtin_amdgcn_sched_barrier(0); }
#define BAR()   { __builtin_amdgcn_s_barrier(); __builtin_amdgcn_sched_barrier(0); }

#define RDNXT(RN)                                                                    \
    {                                                                                \
        _Pragma("unroll")                                                            \
        for (int g = 0; g < 4; ++g)                                                  \
            bfr[g] = *(const bf16x8*)(brdb + (RN) * 16384 + g * 1024);               \
        _Pragma("unroll")                                                            \
        for (int i = 0; i < 4; ++i)                                                  \
            af0[i] = *(const bf16x8*)(ardb + (RN) * 16384 + i * 1024);               \
        _Pragma("unroll")                                                            \
        for (int i = 0; i < 4; ++i)                                                  \
            af1[i] = *(const bf16x8*)(ardb + (RN) * 16384 + 4096 + i * 1024);        \
        __builtin_amdgcn_sched_barrier(0);                                           \
    }

#define MFMA32()                                                                     \
    {                                                                                \
        __builtin_amdgcn_s_setprio(1);                                               \
        _Pragma("unroll")                                                            \
        for (int i = 0; i < 4; ++i)                                                  \
            _Pragma("unroll")                                                        \
            for (int g = 0; g < 4; ++g)                                              \
                acc[i][g] = __builtin_amdgcn_mfma_f32_16x16x32_bf16(af0[i], bfr[g], acc[i][g], 0, 0, 0); \
        _Pragma("unroll")                                                            \
        for (int i = 0; i < 4; ++i)                                                  \
            _Pragma("unroll")                                                        \
            for (int g = 0; g < 4; ++g)                                              \
                acc[4+i][g] = __builtin_amdgcn_mfma_f32_16x16x32_bf16(af1[i], bfr[g], acc[4+i][g], 0, 0, 0); \
        __builtin_amdgcn_s_setprio(0);                                               \
        __builtin_amdgcn_sched_barrier(0);                                           \
    }

    // wm==0: reads at top.  RC = region of slice s.
#define SP0(RC, DOSTAGE, SS, CK)                                                     \
    {                                                                                \
        RDNXT(RC)                                                                    \
        if (DOSTAGE) { stageA2(SS); stageB2(SS); }                                   \
        LGKM0()                                                                      \
        MFMA32()                                                                     \
        if ((CK) == 4) { CKPT4() } else if ((CK) == 1) { CKPT0() }                   \
        BAR()                                                                        \
    }
    // wm==1: reads at tail (slice s+1, region RNX), MFMA on prev-tail frags.
#define SP1(RNX, DORD, DOSTAGE, SS, CK)                                              \
    {                                                                                \
        LGKM0()                                                                      \
        MFMA32()                                                                     \
        if (DORD) RDNXT(RNX)                                                         \
        if (DOSTAGE) { stageA2(SS); stageB2(SS); }                                   \
        if ((CK) == 4) { CKPT4() } else if ((CK) == 1) { CKPT0() }                   \
        BAR()                                                                        \
    }

    // prologue (all waves): stage slices 0,1,2; drain 0,1; barrier.
    stageA2(0); stageB2(0);
    stageA2(1); stageB2(1);
    stageA2(2); stageB2(2);
    CKPT4()
    BAR()

    if (wm == 0) {
        // reads-at-top loop
        for (int s4 = 0; s4 < 31; ++s4) {
            int s = s4 * 4;
            SP0(0, 1, s + 3, 4)
            SP0(1, 1, s + 4, 4)
            SP0(2, 1, s + 5, 4)
            SP0(3, 1, s + 6, 4)
        }
        SP0(0, 1, 127, 4)    // s=124: stage 127; drain stage@123 (slice 126)
        SP0(1, 0, 0,   1)    // s=125: CKPT0 drains stage@124 (slice 127)
        SP0(2, 0, 0,   0)    // s=126
        SP0(3, 0, 0,   0)    // s=127
    } else {
        // reads-at-tail loop (pre-read slice 0 after prologue barrier)
        RDNXT(0)
        for (int s4 = 0; s4 < 31; ++s4) {
            int s = s4 * 4;
            SP1(1, 1, 1, s + 3, 4)
            SP1(2, 1, 1, s + 4, 4)
            SP1(3, 1, 1, s + 5, 4)
            SP1(0, 1, 1, s + 6, 4)
        }
        SP1(1, 1, 1, 127, 4)  // s=124
        SP1(2, 1, 0, 0,   1)  // s=125
        SP1(3, 1, 0, 0,   0)  // s=126: tail-reads slice 127
        SP1(0, 0, 0, 0,   0)  // s=127: no reads after
    }

    // epilogue: C/D layout col = lane&15, row = (lane>>4)*4 + reg
    int    colb = bn * 256 + wn * 64;
    size_t rowb = (size_t)bm * 256 + wm * 128 + (lk << 2);
    #pragma unroll
    for (int g = 0; g < 4; ++g) {
        int col = colb + g * 16 + l16;
        float bv = bias[col];
        #pragma unroll
        for (int f = 0; f < 8; ++f) {
            size_t r0 = rowb + f * 16;
            #pragma unroll
            for (int rg = 0; rg < 4; ++rg)
                C[(r0 + rg) * N_DIM + col] = acc[f][g][rg] + bv;
        }
    }
}

extern "C" void kernel_launch(void* const* d_in, const int* in_sizes, int n_in,
                              void* d_out, int out_size, void* d_ws, size_t ws_size,
                              hipStream_t stream) {
    const float* x    = (const float*)d_in[0];
    const float* W    = (const float*)d_in[1];
    const float* bias = (const float*)d_in[2];
    float* out = (float*)d_out;

    char* ws = (char*)d_ws;
    unsigned short* xb  = (unsigned short*)ws;                                   // 64 MB
    unsigned short* wb  = (unsigned short*)(ws + (size_t)M_DIM * K_DIM * 2);     // 32 MB
    uint16_t*       sel = (uint16_t*)(ws + (size_t)M_DIM * K_DIM * 2
                                         + (size_t)N_DIM * K_DIM * 2);           // 64 KB

    venom_sel <<<dim3(64, 16), 256, 0, stream>>>(W, sel);
    venom_pack<<<dim3((N_DIM * CBN) / 256), 256, 0, stream>>>(W, sel, wb);
    xcvt      <<<dim3((M_DIM * K_DIM / 8) / 256), 256, 0, stream>>>(x, xb);
    gemm256   <<<dim3((M_DIM / 256) * (N_DIM / 256)), 512, 0, stream>>>(xb, wb, bias, out);
}